// Round 1
// baseline (1575.457 us; speedup 1.0000x reference)
//
#include <hip/hip_runtime.h>

#define SCAN_BS 256
#define SCAN_IT 16
#define SCAN_CHUNK (SCAN_BS * SCAN_IT)
#define NVOX 10000000
#define NAVOX 5000000
#define VXYZK 1250000

__device__ __forceinline__ float leakyf(float x) { return x >= 0.0f ? x : 0.1f * x; }

// counters: c[0]=U (num unique voxels), c[1]=A (num assoc groups), c[2]=K-1, c[3]=amask count, c[4]=fg dtype mode
__global__ void k_init(int* c) {
  if (threadIdx.x == 0) { c[0] = 0; c[1] = 0; c[2] = -1; c[3] = 0; c[4] = 0; }
}

// Detect foreground_mask storage: int32 0/1 words never exceed 1; packed uint8 bools do.
__global__ void k_detect_fg(const unsigned* __restrict__ w, int nw, int* __restrict__ c) {
  int i = blockIdx.x * blockDim.x + threadIdx.x;
  if (i < nw && w[i] > 1u) atomicOr(&c[4], 1);
}

__device__ __forceinline__ int fg_get(const void* fgp, int i, int mode) {
  return mode ? (((const unsigned char*)fgp)[i] != 0) : (((const int*)fgp)[i] != 0);
}

__global__ void k_vkey(const float* __restrict__ pc, const int* __restrict__ bidx,
                       int* __restrict__ vkey, unsigned* __restrict__ dense, int N) {
  int i = blockIdx.x * blockDim.x + threadIdx.x;
  if (i >= N) return;
  float x = pc[3 * i], y = pc[3 * i + 1], z = pc[3 * i + 2];
  int xi = (int)floorf((x - (-50.0f)) / 0.4f);
  int yi = (int)floorf((y - (-50.0f)) / 0.4f);
  int zi = (int)floorf((z - (-5.0f)) / 0.4f);
  xi = min(max(xi, 0), 249); yi = min(max(yi, 0), 249); zi = min(max(zi, 0), 19);
  int b = min(max(bidx[i], 0), 7);
  int key = ((b * 250 + xi) * 250 + yi) * 20 + zi;
  vkey[i] = key;
  dense[key] = 1u;
}

__global__ void k_scan_block(unsigned* __restrict__ data, int n, unsigned* __restrict__ bsums) {
  __shared__ unsigned s[SCAN_BS];
  int tid = threadIdx.x;
  long base = (long)blockIdx.x * SCAN_CHUNK + (long)tid * SCAN_IT;
  unsigned v[SCAN_IT];
  unsigned tsum = 0;
#pragma unroll
  for (int j = 0; j < SCAN_IT; ++j) {
    long idx = base + j;
    v[j] = (idx < (long)n) ? data[idx] : 0u;
    tsum += v[j];
  }
  unsigned x = tsum;
  s[tid] = x;
  for (int off = 1; off < SCAN_BS; off <<= 1) {
    __syncthreads();
    unsigned y = (tid >= off) ? s[tid - off] : 0u;
    __syncthreads();
    x += y;
    s[tid] = x;
  }
  if (tid == SCAN_BS - 1) bsums[blockIdx.x] = x;
  unsigned run = x - tsum;
#pragma unroll
  for (int j = 0; j < SCAN_IT; ++j) {
    long idx = base + j;
    if (idx < (long)n) { data[idx] = run; run += v[j]; }
  }
}

__global__ void k_scan_sums(unsigned* __restrict__ data, int n, int* __restrict__ totalOut) {
  __shared__ unsigned s[SCAN_BS];
  int tid = threadIdx.x;
  int base = tid * SCAN_IT;
  unsigned v[SCAN_IT];
  unsigned tsum = 0;
#pragma unroll
  for (int j = 0; j < SCAN_IT; ++j) {
    int idx = base + j;
    v[j] = (idx < n) ? data[idx] : 0u;
    tsum += v[j];
  }
  unsigned x = tsum;
  s[tid] = x;
  for (int off = 1; off < SCAN_BS; off <<= 1) {
    __syncthreads();
    unsigned y = (tid >= off) ? s[tid - off] : 0u;
    __syncthreads();
    x += y;
    s[tid] = x;
  }
  if (tid == SCAN_BS - 1) *totalOut = (int)x;
  unsigned run = x - tsum;
#pragma unroll
  for (int j = 0; j < SCAN_IT; ++j) {
    int idx = base + j;
    if (idx < n) { data[idx] = run; run += v[j]; }
  }
}

__global__ void k_scan_add(unsigned* __restrict__ data, int n, const unsigned* __restrict__ bsums) {
  unsigned add = bsums[blockIdx.x];
  long base = (long)blockIdx.x * SCAN_CHUNK + (long)threadIdx.x * SCAN_IT;
#pragma unroll
  for (int j = 0; j < SCAN_IT; ++j) {
    long idx = base + j;
    if (idx < (long)n) data[idx] += add;
  }
}

__global__ void k_inv_ukey(const int* __restrict__ vkey, const unsigned* __restrict__ dense,
                           const void* __restrict__ fgp, int* __restrict__ inv,
                           int* __restrict__ ukey, int* __restrict__ c, int N) {
  int i = blockIdx.x * blockDim.x + threadIdx.x;
  if (i >= N) return;
  int k = vkey[i];
  int r = (int)dense[k];
  inv[i] = r;
  ukey[r] = k;
  if (fg_get(fgp, i, c[4])) atomicMax(&c[2], r);
}

__global__ void k_cluster_accum(const float* __restrict__ pf, const void* __restrict__ fgp,
                                const int* __restrict__ inv, float* __restrict__ cs,
                                float* __restrict__ cnt, const int* __restrict__ c, int N) {
  int t = blockIdx.x * blockDim.x + threadIdx.x;
  int i = t >> 7;
  if (i >= N) return;
  if (!fg_get(fgp, i, c[4])) return;
  int d = t & 127;
  int r = inv[i];
  atomicAdd(&cs[(size_t)r * 128 + d], pf[(size_t)i * 128 + d]);
  if (d == 0) atomicAdd(&cnt[r], 1.0f);
}

// In-place: csum rows [0,K) -> cfa = leaky(bn(cmean @ Wcp + bcp)); rows >= K stay zero.
__global__ __launch_bounds__(128) void k_proj(
    float* __restrict__ cs, const float* __restrict__ cnt,
    const float* __restrict__ W, const float* __restrict__ bb,
    const float* __restrict__ gg, const float* __restrict__ be,
    const float* __restrict__ mm, const float* __restrict__ vv,
    const int* __restrict__ c, int N) {
  int K = c[2] + 1;
  int base = blockIdx.x * 32;
  if (base >= K) return;
  __shared__ __align__(16) float tile[32][128];
  int d = threadIdx.x;
  for (int p = 0; p < 32; ++p) {
    int r = base + p;
    float val = 0.0f;
    if (r < K) val = cs[(size_t)r * 128 + d] / fmaxf(cnt[r], 1.0f);
    tile[p][d] = val;
  }
  __syncthreads();
  float acc[32];
#pragma unroll
  for (int p = 0; p < 32; ++p) acc[p] = 0.0f;
  for (int k4 = 0; k4 < 32; ++k4) {
    float w0 = W[(4 * k4 + 0) * 128 + d];
    float w1 = W[(4 * k4 + 1) * 128 + d];
    float w2 = W[(4 * k4 + 2) * 128 + d];
    float w3 = W[(4 * k4 + 3) * 128 + d];
#pragma unroll
    for (int p = 0; p < 32; ++p) {
      float4 t4 = *(const float4*)&tile[p][4 * k4];
      acc[p] = fmaf(t4.x, w0, acc[p]);
      acc[p] = fmaf(t4.y, w1, acc[p]);
      acc[p] = fmaf(t4.z, w2, acc[p]);
      acc[p] = fmaf(t4.w, w3, acc[p]);
    }
  }
  float biasd = bb[d], scale = gg[d] / sqrtf(vv[d] + 1e-5f), md = mm[d], bed = be[d];
  for (int p = 0; p < 32; ++p) {
    int r = base + p;
    if (r < K) {
      float pre = acc[p] + biasd;
      cs[(size_t)r * 128 + d] = leakyf((pre - md) * scale + bed);
    }
  }
}

__global__ void k_akey_mark(const int* __restrict__ ukey, int* __restrict__ akey,
                            unsigned* __restrict__ dense, const int* __restrict__ c, int N) {
  int r = blockIdx.x * blockDim.x + threadIdx.x;
  if (r >= N || r >= c[0]) return;
  int uk = ukey[r];
  int ak = (uk / VXYZK / 2) * VXYZK + uk % VXYZK;
  akey[r] = ak;
  dense[ak] = 1u;
}

__global__ void k_ainv(const int* __restrict__ akey, const unsigned* __restrict__ dense,
                       int* __restrict__ ainv, const int* __restrict__ c, int N) {
  int r = blockIdx.x * blockDim.x + threadIdx.x;
  if (r >= N || r >= c[0]) return;
  ainv[r] = (int)dense[akey[r]];
}

__global__ void k_assoc_accum(const float* __restrict__ cfa, const int* __restrict__ ainv,
                              float* __restrict__ asum, float* __restrict__ acnt,
                              const int* __restrict__ c, int N) {
  int t = blockIdx.x * blockDim.x + threadIdx.x;
  int r = t >> 7;
  if (r >= N) return;
  int K = c[2] + 1;
  if (r >= K) return;
  int d = t & 127;
  int g = ainv[r];
  atomicAdd(&asum[(size_t)g * 128 + d], cfa[(size_t)r * 128 + d]);
  if (d == 0) atomicAdd(&acnt[g], 1.0f);
}

// Per-cluster mask: sum_d (cfa[r][d] - asum[g][d]/max(acnt,1)) > 0.
// Per-element difference FIRST so the singleton-group case cancels bit-exactly.
__global__ void k_amask(const float* __restrict__ cfa, const float* __restrict__ asum,
                        const float* __restrict__ acnt, const int* __restrict__ ainv,
                        const int* __restrict__ c, unsigned* __restrict__ flag, int N) {
  int r = blockIdx.x * 4 + (threadIdx.x >> 6);
  int lane = threadIdx.x & 63;
  if (r >= N || r >= c[0]) return;
  int g = ainv[r];
  float mc = fmaxf(acnt[g], 1.0f);
  size_t rb = (size_t)r * 128, gb = (size_t)g * 128;
  float s = (cfa[rb + lane] - asum[gb + lane] / mc)
          + (cfa[rb + 64 + lane] - asum[gb + 64 + lane] / mc);
  for (int off = 32; off > 0; off >>= 1) s += __shfl_down(s, off);
  if (lane == 0) flag[r] = (s > 0.0f) ? 1u : 0u;
}

__global__ void k_count(const int* __restrict__ inv, const unsigned* __restrict__ flag,
                        int* __restrict__ c, int N) {
  int i = blockIdx.x * blockDim.x + threadIdx.x;
  if (i >= N) return;
  if (flag[inv[i]]) atomicAdd(&c[3], 1);
}

__global__ __launch_bounds__(128) void k_final(
    const float* __restrict__ pf, const float* __restrict__ cfa,
    const float* __restrict__ asum, const float* __restrict__ acnt,
    const int* __restrict__ inv, const int* __restrict__ ainv_u,
    const unsigned* __restrict__ flag, const int* __restrict__ c,
    const float* __restrict__ W, const float* __restrict__ bb,
    const float* __restrict__ gg, const float* __restrict__ be,
    const float* __restrict__ mm, const float* __restrict__ vv,
    float* __restrict__ out, int N) {
  __shared__ __align__(16) float tile[32][384];
  __shared__ unsigned sflag[32];
  int d = threadIdx.x;
  int base = blockIdx.x * 32;
  for (int p = 0; p < 32; ++p) {
    int i = base + p;
    float a = 0.0f, bvv = 0.0f, cv = 0.0f;
    if (i < N) {
      int r = inv[i];
      int g = ainv_u[r];
      a = pf[(size_t)i * 128 + d];
      bvv = cfa[(size_t)r * 128 + d];
      cv = asum[(size_t)g * 128 + d] / fmaxf(acnt[g], 1.0f);
      if (d == 0) sflag[p] = flag[r];
    }
    tile[p][d] = a;
    tile[p][128 + d] = bvv;
    tile[p][256 + d] = cv;
  }
  __syncthreads();
  float acc[32];
#pragma unroll
  for (int p = 0; p < 32; ++p) acc[p] = 0.0f;
  for (int k4 = 0; k4 < 96; ++k4) {
    float w0 = W[(4 * k4 + 0) * 128 + d];
    float w1 = W[(4 * k4 + 1) * 128 + d];
    float w2 = W[(4 * k4 + 2) * 128 + d];
    float w3 = W[(4 * k4 + 3) * 128 + d];
#pragma unroll
    for (int p = 0; p < 32; ++p) {
      float4 t4 = *(const float4*)&tile[p][4 * k4];
      acc[p] = fmaf(t4.x, w0, acc[p]);
      acc[p] = fmaf(t4.y, w1, acc[p]);
      acc[p] = fmaf(t4.z, w2, acc[p]);
      acc[p] = fmaf(t4.w, w3, acc[p]);
    }
  }
  float biasd = bb[d], scale = gg[d] / sqrtf(vv[d] + 1e-5f), md = mm[d], bed = be[d];
  bool gate = c[3] > 1;
  for (int p = 0; p < 32; ++p) {
    int i = base + p;
    if (i >= N) break;
    float res;
    if (gate && sflag[p]) {
      float pre = acc[p] + biasd;
      res = leakyf((pre - md) * scale + bed);
    } else {
      res = tile[p][d];
    }
    out[(size_t)i * 128 + d] = res;
  }
}

extern "C" void kernel_launch(void* const* d_in, const int* in_sizes, int n_in,
                              void* d_out, int out_size, void* d_ws, size_t ws_size,
                              hipStream_t stream) {
  (void)n_in; (void)out_size; (void)ws_size;
  const float* pf   = (const float*)d_in[0];
  const float* pc   = (const float*)d_in[1];
  const int*   bidx = (const int*)d_in[2];
  const void*  fgp  = d_in[3];
  const float* Wpf  = (const float*)d_in[5];
  const float* bpf  = (const float*)d_in[6];
  const float* gpf  = (const float*)d_in[7];
  const float* bepf = (const float*)d_in[8];
  const float* mpf  = (const float*)d_in[9];
  const float* vpf  = (const float*)d_in[10];
  const float* Wcp  = (const float*)d_in[11];
  const float* bcp  = (const float*)d_in[12];
  const float* gcp  = (const float*)d_in[13];
  const float* becp = (const float*)d_in[14];
  const float* mcp  = (const float*)d_in[15];
  const float* vcp  = (const float*)d_in[16];
  float* out = (float*)d_out;
  int N = in_sizes[0] / 128;

  char* ws = (char*)d_ws;
  size_t o = 0;
  auto take = [&](size_t bytes) -> void* {
    void* p = ws + o;
    o += (bytes + 255) & ~(size_t)255;
    return p;
  };
  unsigned* dense  = (unsigned*)take((size_t)NVOX * 4);   // reused for assoc keys (5M)
  int* vkey        = (int*)take((size_t)N * 4);
  int* inv         = (int*)take((size_t)N * 4);
  int* ukey        = (int*)take((size_t)N * 4);
  int* akey        = (int*)take((size_t)N * 4);
  int* ainv_u      = (int*)take((size_t)N * 4);
  float* cnt       = (float*)take((size_t)N * 4);
  float* acnt      = (float*)take((size_t)N * 4);
  unsigned* flag   = (unsigned*)take((size_t)N * 4);
  unsigned* bsums  = (unsigned*)take((size_t)4096 * 4);
  int* ctr         = (int*)take(256);
  float* csum      = (float*)take((size_t)N * 128 * 4);   // becomes cfa in place
  float* asum      = (float*)take((size_t)N * 128 * 4);

  hipMemsetAsync(dense, 0, (size_t)NVOX * 4, stream);
  hipMemsetAsync(cnt, 0, (size_t)N * 4, stream);
  hipMemsetAsync(acnt, 0, (size_t)N * 4, stream);
  hipMemsetAsync(csum, 0, (size_t)N * 128 * 4, stream);
  hipMemsetAsync(asum, 0, (size_t)N * 128 * 4, stream);
  k_init<<<1, 64, 0, stream>>>(ctr);

  int nb = (N + 255) / 256;
  int nw = N / 4;
  k_detect_fg<<<(nw + 255) / 256, 256, 0, stream>>>((const unsigned*)fgp, nw, ctr);
  k_vkey<<<nb, 256, 0, stream>>>(pc, bidx, vkey, dense, N);

  int blk1 = (NVOX + SCAN_CHUNK - 1) / SCAN_CHUNK;
  k_scan_block<<<blk1, SCAN_BS, 0, stream>>>(dense, NVOX, bsums);
  k_scan_sums<<<1, SCAN_BS, 0, stream>>>(bsums, blk1, &ctr[0]);
  k_scan_add<<<blk1, SCAN_BS, 0, stream>>>(dense, NVOX, bsums);

  k_inv_ukey<<<nb, 256, 0, stream>>>(vkey, dense, fgp, inv, ukey, ctr, N);
  int nbig = ((N * 128) + 255) / 256;
  k_cluster_accum<<<nbig, 256, 0, stream>>>(pf, fgp, inv, csum, cnt, ctr, N);

  int ntile = (N + 31) / 32;
  k_proj<<<ntile, 128, 0, stream>>>(csum, cnt, Wcp, bcp, gcp, becp, mcp, vcp, ctr, N);

  hipMemsetAsync(dense, 0, (size_t)NAVOX * 4, stream);
  k_akey_mark<<<nb, 256, 0, stream>>>(ukey, akey, dense, ctr, N);
  int blk2 = (NAVOX + SCAN_CHUNK - 1) / SCAN_CHUNK;
  k_scan_block<<<blk2, SCAN_BS, 0, stream>>>(dense, NAVOX, bsums);
  k_scan_sums<<<1, SCAN_BS, 0, stream>>>(bsums, blk2, &ctr[1]);
  k_scan_add<<<blk2, SCAN_BS, 0, stream>>>(dense, NAVOX, bsums);
  k_ainv<<<nb, 256, 0, stream>>>(akey, dense, ainv_u, ctr, N);

  k_assoc_accum<<<nbig, 256, 0, stream>>>(csum, ainv_u, asum, acnt, ctr, N);
  k_amask<<<(N + 3) / 4, 256, 0, stream>>>(csum, asum, acnt, ainv_u, ctr, flag, N);
  k_count<<<nb, 256, 0, stream>>>(inv, flag, ctr, N);

  k_final<<<ntile, 128, 0, stream>>>(pf, csum, asum, acnt, inv, ainv_u, flag, ctr,
                                     Wpf, bpf, gpf, bepf, mpf, vpf, out, N);
}

// Round 2
// 582.203 us; speedup vs baseline: 2.7060x; 2.7060x over previous
//
#include <hip/hip_runtime.h>

#define SCAN_BS 256
#define SCAN_IT 16
#define SCAN_CHUNK (SCAN_BS * SCAN_IT)   // 4096 = 1<<12
#define NVOX 10000000
#define NAVOX 5000000
#define VXYZK 1250000

__device__ __forceinline__ float leakyf(float x) { return x >= 0.0f ? x : 0.1f * x; }

// ctr: [0]=U uniq voxels, [1]=A assoc groups, [2]=K-1, [3]=flagged pts, [4]=fg mode,
//      [5]=mcount (multi clusters), [6]=ncount (valid multi clusters), [7]=cpts (contributing pts)
__global__ void k_init(int* c) {
  int t = threadIdx.x;
  if (t < 8) c[t] = (t == 2) ? -1 : 0;
}

// Detect foreground_mask storage: int32 0/1 words never exceed 1; packed uint8 bools do.
__global__ void k_detect_fg(const unsigned* __restrict__ w, int nw, int* __restrict__ c) {
  int i = blockIdx.x * blockDim.x + threadIdx.x;
  if (i < nw && w[i] > 1u) atomicOr(&c[4], 1);
}

__device__ __forceinline__ int fg_get(const void* fgp, int i, int mode) {
  return mode ? (((const unsigned char*)fgp)[i] != 0) : (((const int*)fgp)[i] != 0);
}

__global__ void k_vkey(const float* __restrict__ pc, const int* __restrict__ bidx,
                       int* __restrict__ vkey, unsigned* __restrict__ dense, int N) {
  int i = blockIdx.x * blockDim.x + threadIdx.x;
  if (i >= N) return;
  float x = pc[3 * i], y = pc[3 * i + 1], z = pc[3 * i + 2];
  int xi = (int)floorf((x - (-50.0f)) / 0.4f);
  int yi = (int)floorf((y - (-50.0f)) / 0.4f);
  int zi = (int)floorf((z - (-5.0f)) / 0.4f);
  xi = min(max(xi, 0), 249); yi = min(max(yi, 0), 249); zi = min(max(zi, 0), 19);
  int b = min(max(bidx[i], 0), 7);
  int key = ((b * 250 + xi) * 250 + yi) * 20 + zi;
  vkey[i] = key;
  dense[key] = 1u;
}

// Writes per-chunk EXCLUSIVE ranks in place + per-chunk sums. No add pass:
// consumers compute rank = dense[k] + bsumsScanned[k>>12].
__global__ void k_scan_block(unsigned* __restrict__ data, int n, unsigned* __restrict__ bsums) {
  __shared__ unsigned s[SCAN_BS];
  int tid = threadIdx.x;
  long base = (long)blockIdx.x * SCAN_CHUNK + (long)tid * SCAN_IT;
  unsigned v[SCAN_IT];
  unsigned tsum = 0;
#pragma unroll
  for (int j = 0; j < SCAN_IT; ++j) {
    long idx = base + j;
    v[j] = (idx < (long)n) ? data[idx] : 0u;
    tsum += v[j];
  }
  unsigned x = tsum;
  s[tid] = x;
  for (int off = 1; off < SCAN_BS; off <<= 1) {
    __syncthreads();
    unsigned y = (tid >= off) ? s[tid - off] : 0u;
    __syncthreads();
    x += y;
    s[tid] = x;
  }
  if (tid == SCAN_BS - 1) bsums[blockIdx.x] = x;
  unsigned run = x - tsum;
#pragma unroll
  for (int j = 0; j < SCAN_IT; ++j) {
    long idx = base + j;
    if (idx < (long)n) { data[idx] = run; run += v[j]; }
  }
}

// Exclusive-scans bsums (n <= 4096) in place, writes total to *totalOut.
__global__ void k_scan_sums(unsigned* __restrict__ data, int n, int* __restrict__ totalOut) {
  __shared__ unsigned s[SCAN_BS];
  int tid = threadIdx.x;
  int base = tid * SCAN_IT;
  unsigned v[SCAN_IT];
  unsigned tsum = 0;
#pragma unroll
  for (int j = 0; j < SCAN_IT; ++j) {
    int idx = base + j;
    v[j] = (idx < n) ? data[idx] : 0u;
    tsum += v[j];
  }
  unsigned x = tsum;
  s[tid] = x;
  for (int off = 1; off < SCAN_BS; off <<= 1) {
    __syncthreads();
    unsigned y = (tid >= off) ? s[tid - off] : 0u;
    __syncthreads();
    x += y;
    s[tid] = x;
  }
  if (tid == SCAN_BS - 1) *totalOut = (int)x;
  unsigned run = x - tsum;
#pragma unroll
  for (int j = 0; j < SCAN_IT; ++j) {
    int idx = base + j;
    if (idx < n) { data[idx] = run; run += v[j]; }
  }
}

__global__ void k_inv_ukey(const int* __restrict__ vkey, const unsigned* __restrict__ dense,
                           const unsigned* __restrict__ bsums, const void* __restrict__ fgp,
                           int* __restrict__ inv, int* __restrict__ ukey,
                           int* __restrict__ c, int N) {
  int i = blockIdx.x * blockDim.x + threadIdx.x;
  if (i >= N) return;
  int k = vkey[i];
  int r = (int)(dense[k] + bsums[k >> 12]);
  inv[i] = r;
  ukey[r] = k;
  if (fg_get(fgp, i, c[4])) atomicMax(&c[2], r);
}

__global__ void k_akey_mark(const int* __restrict__ ukey, int* __restrict__ akey,
                            unsigned* __restrict__ dense, const int* __restrict__ c, int N) {
  int r = blockIdx.x * blockDim.x + threadIdx.x;
  if (r >= N || r >= c[0]) return;
  int uk = ukey[r];
  int ak = (uk / VXYZK / 2) * VXYZK + uk % VXYZK;
  akey[r] = ak;
  dense[ak] = 1u;
}

__global__ void k_ainv(const int* __restrict__ akey, const unsigned* __restrict__ dense,
                       const unsigned* __restrict__ bsums, int* __restrict__ ainv,
                       const int* __restrict__ c, int N) {
  int r = blockIdx.x * blockDim.x + threadIdx.x;
  if (r >= N || r >= c[0]) return;
  int ak = akey[r];
  ainv[r] = (int)(dense[ak] + bsums[ak >> 12]);
}

__global__ void k_gcnt(const int* __restrict__ ainv_u, unsigned* __restrict__ gcnt,
                       const int* __restrict__ c, int N) {
  int r = blockIdx.x * blockDim.x + threadIdx.x;
  if (r >= N || r >= c[0]) return;
  atomicAdd(&gcnt[ainv_u[r]], 1u);
}

// mlist: clusters in multi-member groups (flag can be nonzero only for these).
// nlist: the valid (r < K) subset — the only clusters needing projection/csum/asum.
__global__ void k_build_lists(const int* __restrict__ ainv_u, const unsigned* __restrict__ gcnt,
                              int* __restrict__ mlist, int* __restrict__ nlist,
                              unsigned char* __restrict__ needp, int* __restrict__ c, int N) {
  int r = blockIdx.x * blockDim.x + threadIdx.x;
  if (r >= N || r >= c[0]) return;
  int g = ainv_u[r];
  if (gcnt[g] >= 2u) {
    int mp = atomicAdd(&c[5], 1);
    mlist[mp] = r;
    if (r <= c[2]) {
      needp[r] = 1;
      int np = atomicAdd(&c[6], 1);
      nlist[np] = r;
    }
  }
}

// Zero only the csum/asum rows that will actually be accumulated (dup zero-writes benign).
__global__ void k_zero_rows(const int* __restrict__ mlist, const int* __restrict__ ainv_u,
                            const int* __restrict__ c, float* __restrict__ csum,
                            float* __restrict__ asum) {
  int total = c[5] * 128;
  int stride = gridDim.x * blockDim.x;
  for (int idx = blockIdx.x * blockDim.x + threadIdx.x; idx < total; idx += stride) {
    int r = mlist[idx >> 7];
    int d = idx & 127;
    asum[(size_t)ainv_u[r] * 128 + d] = 0.0f;
    if (r <= c[2]) csum[(size_t)r * 128 + d] = 0.0f;
  }
}

// Foreground points belonging to needed clusters: count into cnt, push into clist.
__global__ void k_point_filter(const void* __restrict__ fgp, const int* __restrict__ inv,
                               const unsigned char* __restrict__ needp, float* __restrict__ cnt,
                               int* __restrict__ clist, int* __restrict__ c, int N) {
  int i = blockIdx.x * blockDim.x + threadIdx.x;
  if (i >= N) return;
  if (!fg_get(fgp, i, c[4])) return;
  int r = inv[i];
  if (!needp[r]) return;
  atomicAdd(&cnt[r], 1.0f);
  int p = atomicAdd(&c[7], 1);
  clist[p] = i;
}

__global__ void k_csum_accum(const float* __restrict__ pf, const int* __restrict__ clist,
                             const int* __restrict__ inv, float* __restrict__ csum,
                             const int* __restrict__ c) {
  int total = c[7] * 128;
  int stride = gridDim.x * blockDim.x;
  for (int idx = blockIdx.x * blockDim.x + threadIdx.x; idx < total; idx += stride) {
    int i = clist[idx >> 7];
    int d = idx & 127;
    int r = inv[i];
    atomicAdd(&csum[(size_t)r * 128 + d], pf[(size_t)i * 128 + d]);
  }
}

// In-place projection of needed clusters only: csum row -> cfa row. 16 rows/block, grid-stride tiles.
__global__ __launch_bounds__(128) void k_proj16(
    float* __restrict__ cs, const float* __restrict__ cnt, const int* __restrict__ nlist,
    const float* __restrict__ W, const float* __restrict__ bb,
    const float* __restrict__ gg, const float* __restrict__ be,
    const float* __restrict__ mm, const float* __restrict__ vv, const int* __restrict__ c) {
  int nc = c[6];
  int ntiles = (nc + 15) >> 4;
  __shared__ __align__(16) float tile[16][128];
  __shared__ int srow[16];
  int d = threadIdx.x;
  for (int tb = blockIdx.x; tb < ntiles; tb += gridDim.x) {
    int base = tb * 16;
    if (d < 16) srow[d] = (base + d < nc) ? nlist[base + d] : -1;
    __syncthreads();
    for (int p = 0; p < 16; ++p) {
      int r = srow[p];
      tile[p][d] = (r >= 0) ? cs[(size_t)r * 128 + d] / fmaxf(cnt[r], 1.0f) : 0.0f;
    }
    __syncthreads();
    float acc[16];
#pragma unroll
    for (int p = 0; p < 16; ++p) acc[p] = 0.0f;
    for (int k4 = 0; k4 < 32; ++k4) {
      float w0 = W[(4 * k4 + 0) * 128 + d];
      float w1 = W[(4 * k4 + 1) * 128 + d];
      float w2 = W[(4 * k4 + 2) * 128 + d];
      float w3 = W[(4 * k4 + 3) * 128 + d];
#pragma unroll
      for (int p = 0; p < 16; ++p) {
        float4 t4 = *(const float4*)&tile[p][4 * k4];
        acc[p] = fmaf(t4.x, w0, acc[p]);
        acc[p] = fmaf(t4.y, w1, acc[p]);
        acc[p] = fmaf(t4.z, w2, acc[p]);
        acc[p] = fmaf(t4.w, w3, acc[p]);
      }
    }
    float biasd = bb[d], scale = gg[d] / sqrtf(vv[d] + 1e-5f), md = mm[d], bed = be[d];
    for (int p = 0; p < 16; ++p) {
      int r = srow[p];
      if (r >= 0) {
        float pre = acc[p] + biasd;
        cs[(size_t)r * 128 + d] = leakyf((pre - md) * scale + bed);
      }
    }
    __syncthreads();
  }
}

__global__ void k_asum_accum(const float* __restrict__ cs, const int* __restrict__ nlist,
                             const int* __restrict__ ainv_u, float* __restrict__ asum,
                             float* __restrict__ acnt, const int* __restrict__ c) {
  int total = c[6] * 128;
  int stride = gridDim.x * blockDim.x;
  for (int idx = blockIdx.x * blockDim.x + threadIdx.x; idx < total; idx += stride) {
    int r = nlist[idx >> 7];
    int d = idx & 127;
    int g = ainv_u[r];
    atomicAdd(&asum[(size_t)g * 128 + d], cs[(size_t)r * 128 + d]);
    if (d == 0) atomicAdd(&acnt[g], 1.0f);
  }
}

// flag only for multi-group clusters; singleton groups cancel bit-exactly -> stay 0 (memset).
// Per-element diff FIRST (exactness), true division (matches reference op).
__global__ void k_amask2(const float* __restrict__ cs, const float* __restrict__ asum,
                         const float* __restrict__ acnt, const int* __restrict__ ainv_u,
                         const int* __restrict__ mlist, const int* __restrict__ c,
                         unsigned* __restrict__ flag) {
  int mcount = c[5];
  int groups = gridDim.x * (blockDim.x >> 6);
  int j0 = blockIdx.x * (blockDim.x >> 6) + (threadIdx.x >> 6);
  int lane = threadIdx.x & 63;
  for (int j = j0; j < mcount; j += groups) {
    int r = mlist[j];
    int g = ainv_u[r];
    float mc = fmaxf(acnt[g], 1.0f);
    bool valid = r <= c[2];
    size_t rb = (size_t)r * 128, gb = (size_t)g * 128;
    float c0 = valid ? cs[rb + lane] : 0.0f;
    float c1 = valid ? cs[rb + 64 + lane] : 0.0f;
    float s = (c0 - asum[gb + lane] / mc) + (c1 - asum[gb + 64 + lane] / mc);
    for (int off = 32; off > 0; off >>= 1) s += __shfl_down(s, off);
    if (lane == 0) flag[r] = (s > 0.0f) ? 1u : 0u;
  }
}

__global__ void k_flagpts(const int* __restrict__ inv, const unsigned* __restrict__ flag,
                          int* __restrict__ plist, int* __restrict__ c, int N) {
  int i = blockIdx.x * blockDim.x + threadIdx.x;
  if (i >= N) return;
  if (flag[inv[i]]) {
    int p = atomicAdd(&c[3], 1);
    plist[p] = i;
  }
}

__global__ void k_copy(const float* __restrict__ pf, float* __restrict__ out, long n4) {
  long stride = (long)gridDim.x * blockDim.x;
  for (long idx = (long)blockIdx.x * blockDim.x + threadIdx.x; idx < n4; idx += stride) {
    ((float4*)out)[idx] = ((const float4*)pf)[idx];
  }
}

// Final GEMM only for flagged points. 16 rows/block, grid-stride tiles, early exit on gate.
__global__ __launch_bounds__(128) void k_fgemm(
    const float* __restrict__ pf, const float* __restrict__ cs,
    const float* __restrict__ asum, const float* __restrict__ acnt,
    const int* __restrict__ inv, const int* __restrict__ ainv_u,
    const int* __restrict__ plist, const int* __restrict__ c,
    const float* __restrict__ W, const float* __restrict__ bb,
    const float* __restrict__ gg, const float* __restrict__ be,
    const float* __restrict__ mm, const float* __restrict__ vv,
    float* __restrict__ out) {
  int pcnt = c[3];
  if (pcnt <= 1) return;  // gate: amask.sum() <= 1 -> pure passthrough
  int ntiles = (pcnt + 15) >> 4;
  __shared__ __align__(16) float tile[16][384];
  __shared__ int si[16], sr[16], sg[16];
  __shared__ float smc[16];
  int t = threadIdx.x;
  int kmax = c[2];
  for (int tb = blockIdx.x; tb < ntiles; tb += gridDim.x) {
    int base = tb * 16;
    if (t < 16) {
      int i = (base + t < pcnt) ? plist[base + t] : -1;
      si[t] = i;
      int r = (i >= 0) ? inv[i] : 0;
      sr[t] = r;
      int g = ainv_u[r];
      sg[t] = g;
      smc[t] = fmaxf(acnt[g], 1.0f);
    }
    __syncthreads();
    for (int e = t; e < 16 * 96; e += 128) {
      int p = e / 96, f4 = e % 96;
      int i = si[p];
      float4 v = make_float4(0.f, 0.f, 0.f, 0.f);
      if (i >= 0) {
        if (f4 < 32) {
          v = ((const float4*)pf)[(size_t)i * 32 + f4];
        } else if (f4 < 64) {
          int r = sr[p];
          if (r <= kmax) v = ((const float4*)cs)[(size_t)r * 32 + (f4 - 32)];
        } else {
          float4 a = ((const float4*)asum)[(size_t)sg[p] * 32 + (f4 - 64)];
          float mc = smc[p];
          v = make_float4(a.x / mc, a.y / mc, a.z / mc, a.w / mc);
        }
      }
      *(float4*)&tile[p][f4 * 4] = v;
    }
    __syncthreads();
    float acc[16];
#pragma unroll
    for (int p = 0; p < 16; ++p) acc[p] = 0.0f;
    for (int k4 = 0; k4 < 96; ++k4) {
      float w0 = W[(4 * k4 + 0) * 128 + t];
      float w1 = W[(4 * k4 + 1) * 128 + t];
      float w2 = W[(4 * k4 + 2) * 128 + t];
      float w3 = W[(4 * k4 + 3) * 128 + t];
#pragma unroll
      for (int p = 0; p < 16; ++p) {
        float4 t4 = *(const float4*)&tile[p][4 * k4];
        acc[p] = fmaf(t4.x, w0, acc[p]);
        acc[p] = fmaf(t4.y, w1, acc[p]);
        acc[p] = fmaf(t4.z, w2, acc[p]);
        acc[p] = fmaf(t4.w, w3, acc[p]);
      }
    }
    float biasd = bb[t], scale = gg[t] / sqrtf(vv[t] + 1e-5f), md = mm[t], bed = be[t];
    for (int p = 0; p < 16; ++p) {
      int i = si[p];
      if (i >= 0) {
        float pre = acc[p] + biasd;
        out[(size_t)i * 128 + t] = leakyf((pre - md) * scale + bed);
      }
    }
    __syncthreads();
  }
}

extern "C" void kernel_launch(void* const* d_in, const int* in_sizes, int n_in,
                              void* d_out, int out_size, void* d_ws, size_t ws_size,
                              hipStream_t stream) {
  (void)n_in; (void)out_size; (void)ws_size;
  const float* pf   = (const float*)d_in[0];
  const float* pc   = (const float*)d_in[1];
  const int*   bidx = (const int*)d_in[2];
  const void*  fgp  = d_in[3];
  const float* Wpf  = (const float*)d_in[5];
  const float* bpf  = (const float*)d_in[6];
  const float* gpf  = (const float*)d_in[7];
  const float* bepf = (const float*)d_in[8];
  const float* mpf  = (const float*)d_in[9];
  const float* vpf  = (const float*)d_in[10];
  const float* Wcp  = (const float*)d_in[11];
  const float* bcp  = (const float*)d_in[12];
  const float* gcp  = (const float*)d_in[13];
  const float* becp = (const float*)d_in[14];
  const float* mcp  = (const float*)d_in[15];
  const float* vcp  = (const float*)d_in[16];
  float* out = (float*)d_out;
  int N = in_sizes[0] / 128;

  char* ws = (char*)d_ws;
  size_t o = 0;
  auto take = [&](size_t bytes) -> void* {
    void* p = ws + o;
    o += (bytes + 255) & ~(size_t)255;
    return p;
  };
  unsigned* dense  = (unsigned*)take((size_t)NVOX * 4);  // reused for assoc keys (5M)
  int* vkey        = (int*)take((size_t)N * 4);          // reused as mlist after inv built
  int* inv         = (int*)take((size_t)N * 4);
  int* ukey        = (int*)take((size_t)N * 4);
  int* akey        = (int*)take((size_t)N * 4);          // reused as plist after ainv built
  int* ainv_u      = (int*)take((size_t)N * 4);
  float* cnt       = (float*)take((size_t)N * 4);
  float* acnt      = (float*)take((size_t)N * 4);
  unsigned* flag   = (unsigned*)take((size_t)N * 4);
  unsigned* gcnt   = (unsigned*)take((size_t)N * 4);
  int* nlist       = (int*)take((size_t)N * 4);
  int* clist       = (int*)take((size_t)N * 4);
  unsigned char* needp = (unsigned char*)take((size_t)N);
  unsigned* bsums1 = (unsigned*)take((size_t)4096 * 4);
  unsigned* bsums2 = (unsigned*)take((size_t)4096 * 4);
  int* ctr         = (int*)take(256);
  float* csum      = (float*)take((size_t)N * 128 * 4);  // becomes cfa in place
  float* asum      = (float*)take((size_t)N * 128 * 4);
  int* mlist = vkey;
  int* plist = akey;

  hipMemsetAsync(dense, 0, (size_t)NVOX * 4, stream);
  hipMemsetAsync(cnt, 0, (size_t)N * 4, stream);
  hipMemsetAsync(acnt, 0, (size_t)N * 4, stream);
  hipMemsetAsync(flag, 0, (size_t)N * 4, stream);
  hipMemsetAsync(gcnt, 0, (size_t)N * 4, stream);
  hipMemsetAsync(needp, 0, (size_t)N, stream);
  k_init<<<1, 64, 0, stream>>>(ctr);

  int nb = (N + 255) / 256;
  int nw = N / 4;
  k_detect_fg<<<(nw + 255) / 256, 256, 0, stream>>>((const unsigned*)fgp, nw, ctr);
  k_vkey<<<nb, 256, 0, stream>>>(pc, bidx, vkey, dense, N);

  int blk1 = (NVOX + SCAN_CHUNK - 1) / SCAN_CHUNK;
  k_scan_block<<<blk1, SCAN_BS, 0, stream>>>(dense, NVOX, bsums1);
  k_scan_sums<<<1, SCAN_BS, 0, stream>>>(bsums1, blk1, &ctr[0]);
  k_inv_ukey<<<nb, 256, 0, stream>>>(vkey, dense, bsums1, fgp, inv, ukey, ctr, N);

  hipMemsetAsync(dense, 0, (size_t)NAVOX * 4, stream);
  k_akey_mark<<<nb, 256, 0, stream>>>(ukey, akey, dense, ctr, N);
  int blk2 = (NAVOX + SCAN_CHUNK - 1) / SCAN_CHUNK;
  k_scan_block<<<blk2, SCAN_BS, 0, stream>>>(dense, NAVOX, bsums2);
  k_scan_sums<<<1, SCAN_BS, 0, stream>>>(bsums2, blk2, &ctr[1]);
  k_ainv<<<nb, 256, 0, stream>>>(akey, dense, bsums2, ainv_u, ctr, N);

  k_gcnt<<<nb, 256, 0, stream>>>(ainv_u, gcnt, ctr, N);
  k_build_lists<<<nb, 256, 0, stream>>>(ainv_u, gcnt, mlist, nlist, needp, ctr, N);

  int gsw = 3125;
  k_zero_rows<<<gsw, 256, 0, stream>>>(mlist, ainv_u, ctr, csum, asum);
  k_point_filter<<<nb, 256, 0, stream>>>(fgp, inv, needp, cnt, clist, ctr, N);
  k_csum_accum<<<gsw, 256, 0, stream>>>(pf, clist, inv, csum, ctr);
  k_proj16<<<gsw, 128, 0, stream>>>(csum, cnt, nlist, Wcp, bcp, gcp, becp, mcp, vcp, ctr);
  k_asum_accum<<<gsw, 256, 0, stream>>>(csum, nlist, ainv_u, asum, acnt, ctr);
  k_amask2<<<1024, 256, 0, stream>>>(csum, asum, acnt, ainv_u, mlist, ctr, flag);
  k_flagpts<<<nb, 256, 0, stream>>>(inv, flag, plist, ctr, N);

  long n4 = (long)N * 32;
  k_copy<<<12800, 256, 0, stream>>>(pf, out, n4);
  k_fgemm<<<gsw, 128, 0, stream>>>(pf, csum, asum, acnt, inv, ainv_u, plist, ctr,
                                   Wpf, bpf, gpf, bepf, mpf, vpf, out);
}

// Round 3
// 465.981 us; speedup vs baseline: 3.3809x; 1.2494x over previous
//
#include <hip/hip_runtime.h>

#define SCAN_BS 256
#define SCAN_IT 16
#define SCAN_CHUNK (SCAN_BS * SCAN_IT)   // 4096 words per chunk = 1<<12
#define NVOX 10000000
#define NAVOX 5000000
#define NWORDS1 312500                   // ceil(NVOX/32)
#define NWORDS2 156250                   // ceil(NAVOX/32)
#define VXYZK 1250000

__device__ __forceinline__ float leakyf(float x) { return x >= 0.0f ? x : 0.1f * x; }

// ctr: [0]=U uniq voxels, [1]=A assoc groups, [2]=K (num fg clusters), [3]=flagged pts,
//      [4]=fg mode, [5]=mcount, [6]=ncount, [7]=cpts.  All-zero init is valid.
__device__ __forceinline__ int fg_get(const void* fgp, int i, int mode) {
  return mode ? (((const unsigned char*)fgp)[i] != 0) : (((const int*)fgp)[i] != 0);
}

// voxelize + mark presence bit + fg dtype detect (int32 0/1 words never exceed 1)
__global__ void k_vkey(const float* __restrict__ pc, const int* __restrict__ bidx,
                       const unsigned* __restrict__ fgw, int nw,
                       int* __restrict__ vkey, unsigned* __restrict__ bits,
                       int* __restrict__ c, int N) {
  int i = blockIdx.x * blockDim.x + threadIdx.x;
  if (i < nw && fgw[i] > 1u) atomicOr(&c[4], 1);
  if (i >= N) return;
  float x = pc[3 * i], y = pc[3 * i + 1], z = pc[3 * i + 2];
  int xi = (int)floorf((x - (-50.0f)) / 0.4f);
  int yi = (int)floorf((y - (-50.0f)) / 0.4f);
  int zi = (int)floorf((z - (-5.0f)) / 0.4f);
  xi = min(max(xi, 0), 249); yi = min(max(yi, 0), 249); zi = min(max(zi, 0), 19);
  int b = min(max(bidx[i], 0), 7);
  int key = ((b * 250 + xi) * 250 + yi) * 20 + zi;
  vkey[i] = key;
  atomicOr(&bits[key >> 5], 1u << (key & 31));
}

// popcount-scan over bit words: per-chunk exclusive word prefix + per-chunk sums.
__global__ void k_scan_pop(const unsigned* __restrict__ bits, int nwords,
                           unsigned* __restrict__ wordpfx, unsigned* __restrict__ bsums) {
  __shared__ unsigned s[SCAN_BS];
  int tid = threadIdx.x;
  long base = (long)blockIdx.x * SCAN_CHUNK + (long)tid * SCAN_IT;
  unsigned v[SCAN_IT];
  unsigned tsum = 0;
#pragma unroll
  for (int j = 0; j < SCAN_IT; ++j) {
    long idx = base + j;
    v[j] = (idx < (long)nwords) ? (unsigned)__popc(bits[idx]) : 0u;
    tsum += v[j];
  }
  unsigned x = tsum;
  s[tid] = x;
  for (int off = 1; off < SCAN_BS; off <<= 1) {
    __syncthreads();
    unsigned y = (tid >= off) ? s[tid - off] : 0u;
    __syncthreads();
    x += y;
    s[tid] = x;
  }
  if (tid == SCAN_BS - 1) bsums[blockIdx.x] = x;
  unsigned run = x - tsum;
#pragma unroll
  for (int j = 0; j < SCAN_IT; ++j) {
    long idx = base + j;
    if (idx < (long)nwords) { wordpfx[idx] = run; run += v[j]; }
  }
}

// exclusive-scan bsums (n <= 4096) in place; total -> *totalOut.
__global__ void k_scan_sums(unsigned* __restrict__ data, int n, int* __restrict__ totalOut) {
  __shared__ unsigned s[SCAN_BS];
  int tid = threadIdx.x;
  int base = tid * SCAN_IT;
  unsigned v[SCAN_IT];
  unsigned tsum = 0;
#pragma unroll
  for (int j = 0; j < SCAN_IT; ++j) {
    int idx = base + j;
    v[j] = (idx < n) ? data[idx] : 0u;
    tsum += v[j];
  }
  unsigned x = tsum;
  s[tid] = x;
  for (int off = 1; off < SCAN_BS; off <<= 1) {
    __syncthreads();
    unsigned y = (tid >= off) ? s[tid - off] : 0u;
    __syncthreads();
    x += y;
    s[tid] = x;
  }
  if (tid == SCAN_BS - 1) *totalOut = (int)x;
  unsigned run = x - tsum;
#pragma unroll
  for (int j = 0; j < SCAN_IT; ++j) {
    int idx = base + j;
    if (idx < n) { data[idx] = run; run += v[j]; }
  }
}

__device__ __forceinline__ int rank_of(int key, const unsigned* bits,
                                       const unsigned* wordpfx, const unsigned* bsums) {
  int w = key >> 5, b = key & 31;
  return (int)(wordpfx[w] + bsums[w >> 12] + (unsigned)__popc(bits[w] & ((1u << b) - 1u)));
}

// inv + ukey + wave-reduced K (one atomicMax per wave).
__global__ void k_inv_ukey(const int* __restrict__ vkey, const unsigned* __restrict__ bits,
                           const unsigned* __restrict__ wordpfx, const unsigned* __restrict__ bsums,
                           const void* __restrict__ fgp, int* __restrict__ inv,
                           int* __restrict__ ukey, int* __restrict__ c, int N) {
  int i = blockIdx.x * blockDim.x + threadIdx.x;
  bool valid = i < N;
  int mode = c[4];
  int r = 0;
  if (valid) {
    int k = vkey[i];
    r = rank_of(k, bits, wordpfx, bsums);
    inv[i] = r;
    ukey[r] = k;
  }
  int fgr = (valid && fg_get(fgp, i, mode)) ? r : -1;
  for (int off = 32; off > 0; off >>= 1) fgr = max(fgr, __shfl_down(fgr, off));
  if ((threadIdx.x & 63) == 0 && fgr >= 0) atomicMax(&c[2], fgr + 1);
}

__global__ void k_akey_mark(const int* __restrict__ ukey, int* __restrict__ akey,
                            unsigned* __restrict__ abits, const int* __restrict__ c, int N) {
  int r = blockIdx.x * blockDim.x + threadIdx.x;
  if (r >= N || r >= c[0]) return;
  int uk = ukey[r];
  int ak = (uk / VXYZK / 2) * VXYZK + uk % VXYZK;
  akey[r] = ak;
  atomicOr(&abits[ak >> 5], 1u << (ak & 31));
}

// ainv + group member count fused.
__global__ void k_ainv(const int* __restrict__ akey, const unsigned* __restrict__ abits,
                       const unsigned* __restrict__ awordpfx, const unsigned* __restrict__ bsums,
                       int* __restrict__ ainv, unsigned* __restrict__ gcnt,
                       const int* __restrict__ c, int N) {
  int r = blockIdx.x * blockDim.x + threadIdx.x;
  if (r >= N || r >= c[0]) return;
  int g = rank_of(akey[r], abits, awordpfx, bsums);
  ainv[r] = g;
  atomicAdd(&gcnt[g], 1u);
}

// mlist: clusters in multi-member groups; nlist: valid subset (r < K).
__global__ void k_build_lists(const int* __restrict__ ainv_u, const unsigned* __restrict__ gcnt,
                              int* __restrict__ mlist, int* __restrict__ nlist,
                              unsigned char* __restrict__ needp, int* __restrict__ c, int N) {
  int r = blockIdx.x * blockDim.x + threadIdx.x;
  if (r >= N || r >= c[0]) return;
  if (gcnt[ainv_u[r]] >= 2u) {
    int mp = atomicAdd(&c[5], 1);
    mlist[mp] = r;
    if (r < c[2]) {
      needp[r] = 1;
      int np = atomicAdd(&c[6], 1);
      nlist[np] = r;
    }
  }
}

// Fused: (A) zero only needed csum/asum rows; (B) filter contributing fg points.
__global__ void k_zero_filter(const int* __restrict__ mlist, const int* __restrict__ ainv_u,
                              const void* __restrict__ fgp, const int* __restrict__ inv,
                              const unsigned char* __restrict__ needp,
                              float* __restrict__ csum, float* __restrict__ asum,
                              float* __restrict__ cnt, int* __restrict__ clist,
                              int* __restrict__ c, int N) {
  int stride = gridDim.x * blockDim.x;
  int tid0 = blockIdx.x * blockDim.x + threadIdx.x;
  int K = c[2];
  int totalA = c[5] * 128;
  for (int idx = tid0; idx < totalA; idx += stride) {
    int r = mlist[idx >> 7];
    int d = idx & 127;
    asum[(size_t)ainv_u[r] * 128 + d] = 0.0f;
    if (r < K) csum[(size_t)r * 128 + d] = 0.0f;
  }
  int mode = c[4];
  for (int i = tid0; i < N; i += stride) {
    if (!fg_get(fgp, i, mode)) continue;
    int r = inv[i];
    if (!needp[r]) continue;
    atomicAdd(&cnt[r], 1.0f);
    int p = atomicAdd(&c[7], 1);
    clist[p] = i;
  }
}

__global__ void k_csum_accum(const float* __restrict__ pf, const int* __restrict__ clist,
                             const int* __restrict__ inv, float* __restrict__ csum,
                             const int* __restrict__ c) {
  int total = c[7] * 128;
  int stride = gridDim.x * blockDim.x;
  for (int idx = blockIdx.x * blockDim.x + threadIdx.x; idx < total; idx += stride) {
    int i = clist[idx >> 7];
    int d = idx & 127;
    atomicAdd(&csum[(size_t)inv[i] * 128 + d], pf[(size_t)i * 128 + d]);
  }
}

// In-place projection of needed clusters: csum row -> cfa row.
__global__ __launch_bounds__(128) void k_proj16(
    float* __restrict__ cs, const float* __restrict__ cnt, const int* __restrict__ nlist,
    const float* __restrict__ W, const float* __restrict__ bb,
    const float* __restrict__ gg, const float* __restrict__ be,
    const float* __restrict__ mm, const float* __restrict__ vv, const int* __restrict__ c) {
  int nc = c[6];
  int ntiles = (nc + 15) >> 4;
  __shared__ __align__(16) float tile[16][128];
  __shared__ int srow[16];
  int d = threadIdx.x;
  for (int tb = blockIdx.x; tb < ntiles; tb += gridDim.x) {
    int base = tb * 16;
    if (d < 16) srow[d] = (base + d < nc) ? nlist[base + d] : -1;
    __syncthreads();
    for (int p = 0; p < 16; ++p) {
      int r = srow[p];
      tile[p][d] = (r >= 0) ? cs[(size_t)r * 128 + d] / fmaxf(cnt[r], 1.0f) : 0.0f;
    }
    __syncthreads();
    float acc[16];
#pragma unroll
    for (int p = 0; p < 16; ++p) acc[p] = 0.0f;
    for (int k4 = 0; k4 < 32; ++k4) {
      float w0 = W[(4 * k4 + 0) * 128 + d];
      float w1 = W[(4 * k4 + 1) * 128 + d];
      float w2 = W[(4 * k4 + 2) * 128 + d];
      float w3 = W[(4 * k4 + 3) * 128 + d];
#pragma unroll
      for (int p = 0; p < 16; ++p) {
        float4 t4 = *(const float4*)&tile[p][4 * k4];
        acc[p] = fmaf(t4.x, w0, acc[p]);
        acc[p] = fmaf(t4.y, w1, acc[p]);
        acc[p] = fmaf(t4.z, w2, acc[p]);
        acc[p] = fmaf(t4.w, w3, acc[p]);
      }
    }
    float biasd = bb[d], scale = gg[d] / sqrtf(vv[d] + 1e-5f), md = mm[d], bed = be[d];
    for (int p = 0; p < 16; ++p) {
      int r = srow[p];
      if (r >= 0) {
        float pre = acc[p] + biasd;
        cs[(size_t)r * 128 + d] = leakyf((pre - md) * scale + bed);
      }
    }
    __syncthreads();
  }
}

__global__ void k_asum_accum(const float* __restrict__ cs, const int* __restrict__ nlist,
                             const int* __restrict__ ainv_u, float* __restrict__ asum,
                             float* __restrict__ acnt, const int* __restrict__ c) {
  int total = c[6] * 128;
  int stride = gridDim.x * blockDim.x;
  for (int idx = blockIdx.x * blockDim.x + threadIdx.x; idx < total; idx += stride) {
    int r = nlist[idx >> 7];
    int d = idx & 127;
    int g = ainv_u[r];
    atomicAdd(&asum[(size_t)g * 128 + d], cs[(size_t)r * 128 + d]);
    if (d == 0) atomicAdd(&acnt[g], 1.0f);
  }
}

// flag for multi-group clusters; per-element diff FIRST (bit-exact singleton cancellation).
__global__ void k_amask2(const float* __restrict__ cs, const float* __restrict__ asum,
                         const float* __restrict__ acnt, const int* __restrict__ ainv_u,
                         const int* __restrict__ mlist, const int* __restrict__ c,
                         unsigned* __restrict__ flag) {
  int mcount = c[5];
  int groups = gridDim.x * (blockDim.x >> 6);
  int j0 = blockIdx.x * (blockDim.x >> 6) + (threadIdx.x >> 6);
  int lane = threadIdx.x & 63;
  int K = c[2];
  for (int j = j0; j < mcount; j += groups) {
    int r = mlist[j];
    int g = ainv_u[r];
    float mc = fmaxf(acnt[g], 1.0f);
    bool valid = r < K;
    size_t rb = (size_t)r * 128, gb = (size_t)g * 128;
    float c0 = valid ? cs[rb + lane] : 0.0f;
    float c1 = valid ? cs[rb + 64 + lane] : 0.0f;
    float s = (c0 - asum[gb + lane] / mc) + (c1 - asum[gb + 64 + lane] / mc);
    for (int off = 32; off > 0; off >>= 1) s += __shfl_down(s, off);
    if (lane == 0) flag[r] = (s > 0.0f) ? 1u : 0u;
  }
}

// Fused passthrough copy + flagged-point list build.
__global__ void k_copy_flag(const float* __restrict__ pf, const int* __restrict__ inv,
                            const unsigned* __restrict__ flag, float* __restrict__ out,
                            int* __restrict__ plist, int* __restrict__ c, int N) {
  long stride = (long)gridDim.x * blockDim.x;
  long tid0 = (long)blockIdx.x * blockDim.x + threadIdx.x;
  for (long i = tid0; i < (long)N; i += stride) {
    if (flag[inv[i]]) {
      int p = atomicAdd(&c[3], 1);
      plist[p] = (int)i;
    }
  }
  long n4 = (long)N * 32;
  for (long idx = tid0; idx < n4; idx += stride) {
    ((float4*)out)[idx] = ((const float4*)pf)[idx];
  }
}

// Final GEMM only for flagged points.
__global__ __launch_bounds__(128) void k_fgemm(
    const float* __restrict__ pf, const float* __restrict__ cs,
    const float* __restrict__ asum, const float* __restrict__ acnt,
    const int* __restrict__ inv, const int* __restrict__ ainv_u,
    const int* __restrict__ plist, const int* __restrict__ c,
    const float* __restrict__ W, const float* __restrict__ bb,
    const float* __restrict__ gg, const float* __restrict__ be,
    const float* __restrict__ mm, const float* __restrict__ vv,
    float* __restrict__ out) {
  int pcnt = c[3];
  if (pcnt <= 1) return;  // gate: amask.sum() <= 1 -> pure passthrough
  int K = c[2];
  int ntiles = (pcnt + 15) >> 4;
  __shared__ __align__(16) float tile[16][384];
  __shared__ int si[16], sr[16], sg[16];
  __shared__ float smc[16];
  int t = threadIdx.x;
  for (int tb = blockIdx.x; tb < ntiles; tb += gridDim.x) {
    int base = tb * 16;
    if (t < 16) {
      int i = (base + t < pcnt) ? plist[base + t] : -1;
      si[t] = i;
      int r = (i >= 0) ? inv[i] : 0;
      sr[t] = r;
      int g = ainv_u[r];
      sg[t] = g;
      smc[t] = fmaxf(acnt[g], 1.0f);
    }
    __syncthreads();
    for (int e = t; e < 16 * 96; e += 128) {
      int p = e / 96, f4 = e % 96;
      int i = si[p];
      float4 v = make_float4(0.f, 0.f, 0.f, 0.f);
      if (i >= 0) {
        if (f4 < 32) {
          v = ((const float4*)pf)[(size_t)i * 32 + f4];
        } else if (f4 < 64) {
          int r = sr[p];
          if (r < K) v = ((const float4*)cs)[(size_t)r * 32 + (f4 - 32)];
        } else {
          float4 a = ((const float4*)asum)[(size_t)sg[p] * 32 + (f4 - 64)];
          float mc = smc[p];
          v = make_float4(a.x / mc, a.y / mc, a.z / mc, a.w / mc);
        }
      }
      *(float4*)&tile[p][f4 * 4] = v;
    }
    __syncthreads();
    float acc[16];
#pragma unroll
    for (int p = 0; p < 16; ++p) acc[p] = 0.0f;
    for (int k4 = 0; k4 < 96; ++k4) {
      float w0 = W[(4 * k4 + 0) * 128 + t];
      float w1 = W[(4 * k4 + 1) * 128 + t];
      float w2 = W[(4 * k4 + 2) * 128 + t];
      float w3 = W[(4 * k4 + 3) * 128 + t];
#pragma unroll
      for (int p = 0; p < 16; ++p) {
        float4 t4 = *(const float4*)&tile[p][4 * k4];
        acc[p] = fmaf(t4.x, w0, acc[p]);
        acc[p] = fmaf(t4.y, w1, acc[p]);
        acc[p] = fmaf(t4.z, w2, acc[p]);
        acc[p] = fmaf(t4.w, w3, acc[p]);
      }
    }
    float biasd = bb[t], scale = gg[t] / sqrtf(vv[t] + 1e-5f), md = mm[t], bed = be[t];
    for (int p = 0; p < 16; ++p) {
      int i = si[p];
      if (i >= 0) {
        float pre = acc[p] + biasd;
        out[(size_t)i * 128 + t] = leakyf((pre - md) * scale + bed);
      }
    }
    __syncthreads();
  }
}

extern "C" void kernel_launch(void* const* d_in, const int* in_sizes, int n_in,
                              void* d_out, int out_size, void* d_ws, size_t ws_size,
                              hipStream_t stream) {
  (void)n_in; (void)out_size; (void)ws_size;
  const float* pf   = (const float*)d_in[0];
  const float* pc   = (const float*)d_in[1];
  const int*   bidx = (const int*)d_in[2];
  const void*  fgp  = d_in[3];
  const float* Wpf  = (const float*)d_in[5];
  const float* bpf  = (const float*)d_in[6];
  const float* gpf  = (const float*)d_in[7];
  const float* bepf = (const float*)d_in[8];
  const float* mpf  = (const float*)d_in[9];
  const float* vpf  = (const float*)d_in[10];
  const float* Wcp  = (const float*)d_in[11];
  const float* bcp  = (const float*)d_in[12];
  const float* gcp  = (const float*)d_in[13];
  const float* becp = (const float*)d_in[14];
  const float* mcp  = (const float*)d_in[15];
  const float* vcp  = (const float*)d_in[16];
  float* out = (float*)d_out;
  int N = in_sizes[0] / 128;

  char* ws = (char*)d_ws;
  size_t o = 0;
  auto take = [&](size_t bytes) -> void* {
    void* p = ws + o;
    o += (bytes + 255) & ~(size_t)255;
    return p;
  };
  // ---- zeroed region (ONE memset) ----
  unsigned* bits   = (unsigned*)take((size_t)NWORDS1 * 4);
  unsigned* abits  = (unsigned*)take((size_t)NWORDS2 * 4);
  float* cnt       = (float*)take((size_t)N * 4);
  float* acnt      = (float*)take((size_t)N * 4);
  unsigned* flag   = (unsigned*)take((size_t)N * 4);
  unsigned* gcnt   = (unsigned*)take((size_t)N * 4);
  unsigned char* needp = (unsigned char*)take((size_t)N);
  int* ctr         = (int*)take(256);
  size_t zeroBytes = o;
  // ---- scratch (no init needed) ----
  unsigned* wordpfx  = (unsigned*)take((size_t)NWORDS1 * 4);
  unsigned* awordpfx = (unsigned*)take((size_t)NWORDS2 * 4);
  unsigned* bsums1 = (unsigned*)take((size_t)4096 * 4);
  unsigned* bsums2 = (unsigned*)take((size_t)4096 * 4);
  int* vkey        = (int*)take((size_t)N * 4);   // reused as mlist after inv built
  int* inv         = (int*)take((size_t)N * 4);
  int* ukey        = (int*)take((size_t)N * 4);
  int* akey        = (int*)take((size_t)N * 4);   // reused as plist after ainv built
  int* ainv_u      = (int*)take((size_t)N * 4);
  int* nlist       = (int*)take((size_t)N * 4);
  int* clist       = (int*)take((size_t)N * 4);
  float* csum      = (float*)take((size_t)N * 128 * 4);  // becomes cfa in place
  float* asum      = (float*)take((size_t)N * 128 * 4);
  int* mlist = vkey;
  int* plist = akey;

  hipMemsetAsync(ws, 0, zeroBytes, stream);

  int nb = (N + 255) / 256;
  int nw = N / 4;
  k_vkey<<<nb, 256, 0, stream>>>(pc, bidx, (const unsigned*)fgp, nw, vkey, bits, ctr, N);

  int blk1 = (NWORDS1 + SCAN_CHUNK - 1) / SCAN_CHUNK;   // 77
  k_scan_pop<<<blk1, SCAN_BS, 0, stream>>>(bits, NWORDS1, wordpfx, bsums1);
  k_scan_sums<<<1, SCAN_BS, 0, stream>>>(bsums1, blk1, &ctr[0]);
  k_inv_ukey<<<nb, 256, 0, stream>>>(vkey, bits, wordpfx, bsums1, fgp, inv, ukey, ctr, N);

  k_akey_mark<<<nb, 256, 0, stream>>>(ukey, akey, abits, ctr, N);
  int blk2 = (NWORDS2 + SCAN_CHUNK - 1) / SCAN_CHUNK;   // 39
  k_scan_pop<<<blk2, SCAN_BS, 0, stream>>>(abits, NWORDS2, awordpfx, bsums2);
  k_scan_sums<<<1, SCAN_BS, 0, stream>>>(bsums2, blk2, &ctr[1]);
  k_ainv<<<nb, 256, 0, stream>>>(akey, abits, awordpfx, bsums2, ainv_u, gcnt, ctr, N);

  k_build_lists<<<nb, 256, 0, stream>>>(ainv_u, gcnt, mlist, nlist, needp, ctr, N);
  k_zero_filter<<<1024, 256, 0, stream>>>(mlist, ainv_u, fgp, inv, needp,
                                          csum, asum, cnt, clist, ctr, N);
  k_csum_accum<<<1024, 256, 0, stream>>>(pf, clist, inv, csum, ctr);
  k_proj16<<<512, 128, 0, stream>>>(csum, cnt, nlist, Wcp, bcp, gcp, becp, mcp, vcp, ctr);
  k_asum_accum<<<512, 256, 0, stream>>>(csum, nlist, ainv_u, asum, acnt, ctr);
  k_amask2<<<512, 256, 0, stream>>>(csum, asum, acnt, ainv_u, mlist, ctr, flag);

  k_copy_flag<<<4096, 256, 0, stream>>>(pf, inv, flag, out, plist, ctr, N);
  k_fgemm<<<1024, 128, 0, stream>>>(pf, csum, asum, acnt, inv, ainv_u, plist, ctr,
                                    Wpf, bpf, gpf, bepf, mpf, vpf, out);
}